// Round 1
// baseline (291.738 us; speedup 1.0000x reference)
//
#include <hip/hip_runtime.h>

#define BATCH 64
#define LLEN 65536
#define NW 2047
#define STATS 321

__device__ __forceinline__ float waveReduceSum(float v) {
#pragma unroll
    for (int off = 32; off >= 1; off >>= 1) v += __shfl_xor(v, off, 64);
    return v;
}

// ---------------- global histogram (per row) ----------------
__global__ __launch_bounds__(256) void hist_kernel(const int* __restrict__ x,
                                                   int* __restrict__ hist) {
    __shared__ int lh[256];
    const int row = blockIdx.y;
    lh[threadIdx.x] = 0;
    __syncthreads();
    const int base = row * LLEN + blockIdx.x * 8192;
#pragma unroll 4
    for (int it = 0; it < 32; ++it) {
        int v = x[base + it * 256 + threadIdx.x];
        v = min(max(v, 0), 255);
        atomicAdd(&lh[v], 1);
    }
    __syncthreads();
    atomicAdd(&hist[row * 256 + threadIdx.x], lh[threadIdx.x]);
}

// ---------------- windowed entropy: one wave per 64-byte window ----------------
__global__ __launch_bounds__(256) void went_kernel(const int* __restrict__ x,
                                                   int* __restrict__ cnt) {
    const int gid = blockIdx.x * 256 + (int)threadIdx.x;
    const int wid = gid >> 6;          // global wave id == window id
    const int lane = threadIdx.x & 63;
    const int row = wid / NW;
    const int w = wid - row * NW;

    int v = x[row * LLEN + (w << 5) + lane];
    v = min(max(v, 0), 255);

    // match-count across the wave via 8 ballots
    unsigned long long m = ~0ull;
#pragma unroll
    for (int k = 0; k < 8; ++k) {
        unsigned long long b = __ballot((v >> k) & 1);
        m &= ((v >> k) & 1) ? b : ~b;
    }
    const float c = (float)__popcll(m);

    // per-lane share of entropy: term(c)/c = -(1/64)*log2(c/64)
    float e = -0.015625f * log2f(c * 0.015625f);
    e = waveReduceSum(e);  // butterfly: all lanes hold identical entropy

    // CDF bin: lane k holds level_k = linspace(0,8,64)[k]
    const float lv = (lane == 63) ? 8.0f : (float)lane * (8.0f / 63.0f);
    const unsigned long long mask = __ballot(e <= lv);
    if (lane == 0) {
        const int j = __ffsll((long long)mask) - 1;  // first level >= entropy
        atomicAdd(&cnt[row * 64 + j], 1);
    }
}

// ---------------- assemble feature vector [B, 321] ----------------
__global__ __launch_bounds__(256) void feats_kernel(const int* __restrict__ hist,
                                                    const int* __restrict__ cnt,
                                                    float* __restrict__ feats) {
    __shared__ float red[4];
    const int row = blockIdx.x;
    const int t = threadIdx.x;
    const int c = hist[row * 256 + t];
    const float p = (float)c * (1.0f / 65536.0f);
    feats[row * STATS + t] = p;  // normalized hist
    const float term = (c > 0) ? (-p * log2f(p + 1e-10f)) : 0.0f;
    const float s = waveReduceSum(term);
    if ((t & 63) == 0) red[t >> 6] = s;
    __syncthreads();
    if (t == 0) {
        feats[row * STATS + 256] = red[0] + red[1] + red[2] + red[3];  // global entropy
        int cum = 0;
        for (int k = 0; k < 64; ++k) {
            cum += cnt[row * 64 + k];
            feats[row * STATS + 257 + k] = (float)cum / 2047.0f;  // CDF
        }
    }
}

// ---------------- MLP: one block per row, one thread per hidden unit ----------------
__device__ __forceinline__ float blockSum512(float v, float* red) {
    const float s = waveReduceSum(v);
    if ((threadIdx.x & 63) == 0) red[threadIdx.x >> 6] = s;
    __syncthreads();
    const float tot = red[0] + red[1] + red[2] + red[3] + red[4] + red[5] + red[6] + red[7];
    __syncthreads();
    return tot;
}

__global__ __launch_bounds__(512) void mlp_kernel(
    const float* __restrict__ feats,
    const float* __restrict__ W1, const float* __restrict__ b1,
    const float* __restrict__ g1, const float* __restrict__ be1,
    const float* __restrict__ W2, const float* __restrict__ b2,
    const float* __restrict__ g2, const float* __restrict__ be2,
    const float* __restrict__ W3, const float* __restrict__ b3,
    float* __restrict__ out) {
    __shared__ float sa[512];
    __shared__ float sb[512];
    __shared__ float red[8];
    const int row = blockIdx.x;
    const int t = threadIdx.x;

    if (t < STATS) sa[t] = feats[row * STATS + t];
    __syncthreads();

    // layer 1: [321] @ [321,512]
    float acc = b1[t];
#pragma unroll 4
    for (int i = 0; i < STATS; ++i) acc += sa[i] * W1[i * 512 + t];
    float mu = blockSum512(acc, red) * (1.0f / 512.0f);
    float d = acc - mu;
    float var = blockSum512(d * d, red) * (1.0f / 512.0f);
    float h = d * rsqrtf(var + 1e-5f) * g1[t] + be1[t];
    sb[t] = fmaxf(h, 0.0f);
    __syncthreads();

    // layer 2: [512] @ [512,512]
    float acc2 = b2[t];
#pragma unroll 4
    for (int i = 0; i < 512; ++i) acc2 += sb[i] * W2[i * 512 + t];
    mu = blockSum512(acc2, red) * (1.0f / 512.0f);
    d = acc2 - mu;
    var = blockSum512(d * d, red) * (1.0f / 512.0f);
    h = d * rsqrtf(var + 1e-5f) * g2[t] + be2[t];
    sa[t] = fmaxf(h, 0.0f);  // reuse sa (safe: barriers inside blockSum512)
    __syncthreads();

    // layer 3: [512] @ [512,256]
    if (t < 256) {
        float o = b3[t];
#pragma unroll 4
        for (int i = 0; i < 512; ++i) o += sa[i] * W3[i * 256 + t];
        out[row * 256 + t] = o;
    }
}

extern "C" void kernel_launch(void* const* d_in, const int* in_sizes, int n_in,
                              void* d_out, int out_size, void* d_ws, size_t ws_size,
                              hipStream_t stream) {
    const int* x = (const int*)d_in[0];
    const float* W1 = (const float*)d_in[1];
    const float* b1 = (const float*)d_in[2];
    const float* g1 = (const float*)d_in[3];
    const float* be1 = (const float*)d_in[4];
    const float* W2 = (const float*)d_in[5];
    const float* b2 = (const float*)d_in[6];
    const float* g2 = (const float*)d_in[7];
    const float* be2 = (const float*)d_in[8];
    const float* W3 = (const float*)d_in[9];
    const float* b3 = (const float*)d_in[10];
    float* out = (float*)d_out;

    char* ws = (char*)d_ws;
    int* hist = (int*)ws;                  // 64*256*4 = 65536 B
    int* cnt = (int*)(ws + 65536);         // 64*64*4  = 16384 B
    float* feats = (float*)(ws + 81920);   // 64*321*4 = 82176 B

    hipMemsetAsync(d_ws, 0, 81920, stream);  // zero hist + cnt (ws is poisoned)
    hist_kernel<<<dim3(8, 64), 256, 0, stream>>>(x, hist);
    went_kernel<<<dim3((BATCH * NW) / 4), 256, 0, stream>>>(x, cnt);
    feats_kernel<<<BATCH, 256, 0, stream>>>(hist, cnt, feats);
    mlp_kernel<<<BATCH, 512, 0, stream>>>(feats, W1, b1, g1, be1, W2, b2, g2, be2, W3, b3, out);
}

// Round 2
// 213.783 us; speedup vs baseline: 1.3646x; 1.3646x over previous
//
#include <hip/hip_runtime.h>

#define BATCH 64
#define LLEN 65536
#define NW 2047
#define STATS 321

__device__ __forceinline__ float waveReduceSum(float v) {
#pragma unroll
    for (int off = 32; off >= 1; off >>= 1) v += __shfl_xor(v, off, 64);
    return v;
}

// ---------------- global histogram (per row) ----------------
__global__ __launch_bounds__(256) void hist_kernel(const int* __restrict__ x,
                                                   int* __restrict__ hist) {
    __shared__ int lh[256];
    const int row = blockIdx.y;
    lh[threadIdx.x] = 0;
    __syncthreads();
    const int base = row * LLEN + blockIdx.x * 8192;
#pragma unroll 4
    for (int it = 0; it < 32; ++it) {
        int v = x[base + it * 256 + threadIdx.x];
        v = min(max(v, 0), 255);
        atomicAdd(&lh[v], 1);
    }
    __syncthreads();
    atomicAdd(&hist[row * 256 + threadIdx.x], lh[threadIdx.x]);
}

// ---------------- windowed entropy: one wave per 64-byte window ----------------
__global__ __launch_bounds__(256) void went_kernel(const int* __restrict__ x,
                                                   int* __restrict__ cnt) {
    const int gid = blockIdx.x * 256 + (int)threadIdx.x;
    const int wid = gid >> 6;          // global wave id == window id
    const int lane = threadIdx.x & 63;
    const int row = wid / NW;
    const int w = wid - row * NW;

    int v = x[row * LLEN + (w << 5) + lane];
    v = min(max(v, 0), 255);

    // match-count across the wave via 8 ballots
    unsigned long long m = ~0ull;
#pragma unroll
    for (int k = 0; k < 8; ++k) {
        unsigned long long b = __ballot((v >> k) & 1);
        m &= ((v >> k) & 1) ? b : ~b;
    }
    const float c = (float)__popcll(m);

    // per-lane share of entropy: term(c)/c = -(1/64)*log2(c/64)
    float e = -0.015625f * log2f(c * 0.015625f);
    e = waveReduceSum(e);  // butterfly: all lanes hold identical entropy

    // CDF bin: lane k holds level_k = linspace(0,8,64)[k]
    const float lv = (lane == 63) ? 8.0f : (float)lane * (8.0f / 63.0f);
    const unsigned long long mask = __ballot(e <= lv);
    if (lane == 0) {
        const int j = __ffsll((long long)mask) - 1;  // first level >= entropy
        atomicAdd(&cnt[row * 64 + j], 1);
    }
}

// ---------------- assemble feature vector [B, 321] ----------------
__global__ __launch_bounds__(256) void feats_kernel(const int* __restrict__ hist,
                                                    const int* __restrict__ cnt,
                                                    float* __restrict__ feats) {
    __shared__ float red[4];
    const int row = blockIdx.x;
    const int t = threadIdx.x;
    const int c = hist[row * 256 + t];
    const float p = (float)c * (1.0f / 65536.0f);
    feats[row * STATS + t] = p;  // normalized hist
    const float term = (c > 0) ? (-p * log2f(p + 1e-10f)) : 0.0f;
    const float s = waveReduceSum(term);
    if ((t & 63) == 0) red[t >> 6] = s;
    __syncthreads();
    if (t == 0) {
        feats[row * STATS + 256] = red[0] + red[1] + red[2] + red[3];  // global entropy
        int cum = 0;
        for (int k = 0; k < 64; ++k) {
            cum += cnt[row * 64 + k];
            feats[row * STATS + 257 + k] = (float)cum / 2047.0f;  // CDF
        }
    }
}

// ---------------- MLP layer 1: feats[64,321] @ W1[321,512] + b1 -> raw1 ----------------
// grid (4, 64): blockIdx.x = 128-col tile, blockIdx.y = row. 256 threads.
// thread t: cols c..c+3 (float4), K-group kg = t>>5 (8 groups of 41).
__global__ __launch_bounds__(256) void gemm_first_kernel(
    const float* __restrict__ feats, const float* __restrict__ W,
    const float* __restrict__ b, float* __restrict__ out) {
    __shared__ float sa[STATS];
    __shared__ float part[8][128];
    const int row = blockIdx.y;
    const int t = threadIdx.x;
    for (int i = t; i < STATS; i += 256) sa[i] = feats[row * STATS + i];
    __syncthreads();

    const int c = blockIdx.x * 128 + (t & 31) * 4;
    const int kg = t >> 5;
    const int klo = kg * 41;
    const int khi = min(klo + 41, STATS);
    float4 acc = {0.f, 0.f, 0.f, 0.f};
    for (int k = klo; k < khi; ++k) {
        const float a = sa[k];
        const float4 w = *(const float4*)&W[k * 512 + c];
        acc.x = fmaf(a, w.x, acc.x);
        acc.y = fmaf(a, w.y, acc.y);
        acc.z = fmaf(a, w.z, acc.z);
        acc.w = fmaf(a, w.w, acc.w);
    }
    *(float4*)&part[kg][(t & 31) * 4] = acc;
    __syncthreads();
    if (t < 128) {
        float o = b[blockIdx.x * 128 + t];
#pragma unroll
        for (int g = 0; g < 8; ++g) o += part[g][t];
        out[row * 512 + blockIdx.x * 128 + t] = o;
    }
}

// ---------------- MLP layers 2/3: LN(raw)+ReLU then @ W + b ----------------
// grid (NOUT/128, 64). 256 threads. Input is always 512-dim raw pre-LN acts.
template <int NOUT>
__global__ __launch_bounds__(256) void gemm_ln_kernel(
    const float* __restrict__ raw, const float* __restrict__ g,
    const float* __restrict__ be, const float* __restrict__ W,
    const float* __restrict__ b, float* __restrict__ out) {
    __shared__ float sa[512];
    __shared__ float red[4];
    __shared__ float part[8][128];
    const int row = blockIdx.y;
    const int t = threadIdx.x;

    const float v1 = raw[row * 512 + t];
    const float v2 = raw[row * 512 + 256 + t];
    float s = waveReduceSum(v1 + v2);
    if ((t & 63) == 0) red[t >> 6] = s;
    __syncthreads();
    const float mu = (red[0] + red[1] + red[2] + red[3]) * (1.0f / 512.0f);
    __syncthreads();
    float q = waveReduceSum(v1 * v1 + v2 * v2);
    if ((t & 63) == 0) red[t >> 6] = q;
    __syncthreads();
    const float var = (red[0] + red[1] + red[2] + red[3]) * (1.0f / 512.0f) - mu * mu;
    const float rs = rsqrtf(var + 1e-5f);
    sa[t] = fmaxf((v1 - mu) * rs * g[t] + be[t], 0.0f);
    sa[t + 256] = fmaxf((v2 - mu) * rs * g[t + 256] + be[t + 256], 0.0f);
    __syncthreads();

    const int c = blockIdx.x * 128 + (t & 31) * 4;
    const int kg = t >> 5;
    float4 acc = {0.f, 0.f, 0.f, 0.f};
#pragma unroll 8
    for (int k = kg * 64; k < kg * 64 + 64; ++k) {
        const float a = sa[k];
        const float4 w = *(const float4*)&W[k * NOUT + c];
        acc.x = fmaf(a, w.x, acc.x);
        acc.y = fmaf(a, w.y, acc.y);
        acc.z = fmaf(a, w.z, acc.z);
        acc.w = fmaf(a, w.w, acc.w);
    }
    *(float4*)&part[kg][(t & 31) * 4] = acc;
    __syncthreads();
    if (t < 128) {
        float o = b[blockIdx.x * 128 + t];
#pragma unroll
        for (int gi = 0; gi < 8; ++gi) o += part[gi][t];
        out[row * NOUT + blockIdx.x * 128 + t] = o;
    }
}

extern "C" void kernel_launch(void* const* d_in, const int* in_sizes, int n_in,
                              void* d_out, int out_size, void* d_ws, size_t ws_size,
                              hipStream_t stream) {
    const int* x = (const int*)d_in[0];
    const float* W1 = (const float*)d_in[1];
    const float* b1 = (const float*)d_in[2];
    const float* g1 = (const float*)d_in[3];
    const float* be1 = (const float*)d_in[4];
    const float* W2 = (const float*)d_in[5];
    const float* b2 = (const float*)d_in[6];
    const float* g2 = (const float*)d_in[7];
    const float* be2 = (const float*)d_in[8];
    const float* W3 = (const float*)d_in[9];
    const float* b3 = (const float*)d_in[10];
    float* out = (float*)d_out;

    char* ws = (char*)d_ws;
    int* hist = (int*)ws;                    // 64*256*4 = 65536 B
    int* cnt = (int*)(ws + 65536);           // 64*64*4  = 16384 B
    float* feats = (float*)(ws + 81920);     // 64*321*4 = 82176 B -> ends 164096
    float* raw1 = (float*)(ws + 164096);     // 64*512*4 = 131072 B -> ends 295168
    float* raw2 = (float*)(ws + 295168);     // 64*512*4 = 131072 B -> ends 426240

    hipMemsetAsync(d_ws, 0, 81920, stream);  // zero hist + cnt (ws is poisoned)
    hist_kernel<<<dim3(8, 64), 256, 0, stream>>>(x, hist);
    went_kernel<<<dim3((BATCH * NW) / 4), 256, 0, stream>>>(x, cnt);
    feats_kernel<<<BATCH, 256, 0, stream>>>(hist, cnt, feats);
    gemm_first_kernel<<<dim3(4, BATCH), 256, 0, stream>>>(feats, W1, b1, raw1);
    gemm_ln_kernel<512><<<dim3(4, BATCH), 256, 0, stream>>>(raw1, g1, be1, W2, b2, raw2);
    gemm_ln_kernel<256><<<dim3(2, BATCH), 256, 0, stream>>>(raw2, g2, be2, W3, b3, out);
}

// Round 3
// 143.075 us; speedup vs baseline: 2.0391x; 1.4942x over previous
//
#include <hip/hip_runtime.h>

#define BATCH 64
#define LLEN 65536
#define NW 2047
#define STATS 321
#define WPB 64  // windows per block in went_kernel (4 waves x 16)

__device__ __forceinline__ float waveReduceSum(float v) {
#pragma unroll
    for (int off = 32; off >= 1; off >>= 1) v += __shfl_xor(v, off, 64);
    return v;
}

// ---------------- global histogram (per row) ----------------
__global__ __launch_bounds__(256) void hist_kernel(const int* __restrict__ x,
                                                   int* __restrict__ hist) {
    __shared__ int lh[256];
    const int row = blockIdx.y;
    lh[threadIdx.x] = 0;
    __syncthreads();
    const int base = row * LLEN + blockIdx.x * 8192;
#pragma unroll 4
    for (int it = 0; it < 32; ++it) {
        int v = x[base + it * 256 + threadIdx.x];
        v = min(max(v, 0), 255);
        atomicAdd(&lh[v], 1);
    }
    __syncthreads();
    atomicAdd(&hist[row * 256 + threadIdx.x], lh[threadIdx.x]);
}

// ---------------- windowed entropy: wave per window, 16 windows/wave ----------------
// grid: (ceil(NW/WPB)=32, BATCH). Block aggregates CDF bins in LDS, one
// global atomic per bin per block (kills the 131k-atomic contention).
__global__ __launch_bounds__(256) void went_kernel(const int* __restrict__ x,
                                                   int* __restrict__ cnt) {
    __shared__ int lcnt[64];
    const int row = blockIdx.y;
    const int t = threadIdx.x;
    if (t < 64) lcnt[t] = 0;
    __syncthreads();
    const int lane = t & 63;
    const int wave = t >> 6;
    const float lv = (lane == 63) ? 8.0f : (float)lane * (8.0f / 63.0f);
    const int wbase = blockIdx.x * WPB + wave * (WPB / 4);
    const int rbase = row * LLEN;
#pragma unroll 2
    for (int i = 0; i < WPB / 4; ++i) {
        const int w = wbase + i;
        if (w < NW) {
            int v = x[rbase + (w << 5) + lane];
            v = min(max(v, 0), 255);
            // match-count across the wave via 8 ballots
            unsigned long long m = ~0ull;
#pragma unroll
            for (int k = 0; k < 8; ++k) {
                unsigned long long b = __ballot((v >> k) & 1);
                m &= ((v >> k) & 1) ? b : ~b;
            }
            const float c = (float)__popcll(m);
            // per-lane share: term(c)/c = -(1/64)*log2(c/64); butterfly broadcasts sum
            float e = waveReduceSum(-0.015625f * log2f(c * 0.015625f));
            const unsigned long long mask = __ballot(e <= lv);
            if (lane == 0) atomicAdd(&lcnt[__ffsll((long long)mask) - 1], 1);
        }
    }
    __syncthreads();
    if (t < 64) {
        const int c = lcnt[t];
        if (c) atomicAdd(&cnt[row * 64 + t], c);
    }
}

// ---------------- assemble feature vector [B, 321] ----------------
__global__ __launch_bounds__(256) void feats_kernel(const int* __restrict__ hist,
                                                    const int* __restrict__ cnt,
                                                    float* __restrict__ feats) {
    __shared__ float red[4];
    const int row = blockIdx.x;
    const int t = threadIdx.x;
    const int c = hist[row * 256 + t];
    const float p = (float)c * (1.0f / 65536.0f);
    feats[row * STATS + t] = p;  // normalized hist
    const float term = (c > 0) ? (-p * log2f(p + 1e-10f)) : 0.0f;
    const float s = waveReduceSum(term);
    if ((t & 63) == 0) red[t >> 6] = s;
    __syncthreads();
    if (t == 0) {
        feats[row * STATS + 256] = red[0] + red[1] + red[2] + red[3];  // global entropy
        int cum = 0;
        for (int k = 0; k < 64; ++k) {
            cum += cnt[row * 64 + k];
            feats[row * STATS + 257 + k] = (float)cum / 2047.0f;  // CDF
        }
    }
}

// ---------------- MLP layer 1: feats[64,321] @ W1[321,512] + b1 -> raw1 ----------------
// grid (8, 64): 64-col tiles, 512 blocks (2/CU). K-split 16 ways (21 iters max).
__global__ __launch_bounds__(256) void gemm_first_kernel(
    const float* __restrict__ feats, const float* __restrict__ W,
    const float* __restrict__ b, float* __restrict__ out) {
    __shared__ float sa[STATS];
    __shared__ float part[16][64];
    const int row = blockIdx.y;
    const int t = threadIdx.x;
    for (int i = t; i < STATS; i += 256) sa[i] = feats[row * STATS + i];
    __syncthreads();

    const int cl = (t & 15) * 4;
    const int c = blockIdx.x * 64 + cl;
    const int kg = t >> 4;
    const int klo = kg * 21;
    const int khi = min(klo + 21, STATS);
    float4 acc = {0.f, 0.f, 0.f, 0.f};
    for (int k = klo; k < khi; ++k) {
        const float a = sa[k];
        const float4 w = *(const float4*)&W[k * 512 + c];
        acc.x = fmaf(a, w.x, acc.x);
        acc.y = fmaf(a, w.y, acc.y);
        acc.z = fmaf(a, w.z, acc.z);
        acc.w = fmaf(a, w.w, acc.w);
    }
    *(float4*)&part[kg][cl] = acc;
    __syncthreads();
    if (t < 64) {
        float o = b[blockIdx.x * 64 + t];
#pragma unroll
        for (int g = 0; g < 16; ++g) o += part[g][t];
        out[row * 512 + blockIdx.x * 64 + t] = o;
    }
}

// ---------------- MLP layers 2/3: LN(raw)+ReLU then @ W + b ----------------
// grid (NOUT/CPB, 64). 256 threads. Input is 512-dim raw pre-LN activations.
template <int NOUT, int CPB>
__global__ __launch_bounds__(256) void gemm_ln_kernel(
    const float* __restrict__ raw, const float* __restrict__ g,
    const float* __restrict__ be, const float* __restrict__ W,
    const float* __restrict__ b, float* __restrict__ out) {
    constexpr int TC = CPB / 4;    // threads in col dim
    constexpr int KG = 256 / TC;   // k groups
    constexpr int KI = 512 / KG;   // k iters per thread
    __shared__ float sa[512];
    __shared__ float red[4];
    __shared__ float part[KG][CPB];
    const int row = blockIdx.y;
    const int t = threadIdx.x;

    const float v1 = raw[row * 512 + t];
    const float v2 = raw[row * 512 + 256 + t];
    float s = waveReduceSum(v1 + v2);
    if ((t & 63) == 0) red[t >> 6] = s;
    __syncthreads();
    const float mu = (red[0] + red[1] + red[2] + red[3]) * (1.0f / 512.0f);
    __syncthreads();
    float q = waveReduceSum(v1 * v1 + v2 * v2);
    if ((t & 63) == 0) red[t >> 6] = q;
    __syncthreads();
    const float var = (red[0] + red[1] + red[2] + red[3]) * (1.0f / 512.0f) - mu * mu;
    const float rs = rsqrtf(var + 1e-5f);
    sa[t] = fmaxf((v1 - mu) * rs * g[t] + be[t], 0.0f);
    sa[t + 256] = fmaxf((v2 - mu) * rs * g[t + 256] + be[t + 256], 0.0f);
    __syncthreads();

    const int cl = (t % TC) * 4;
    const int c = blockIdx.x * CPB + cl;
    const int kg = t / TC;
    float4 acc = {0.f, 0.f, 0.f, 0.f};
#pragma unroll
    for (int i = 0; i < KI; ++i) {
        const int k = kg * KI + i;
        const float a = sa[k];
        const float4 w = *(const float4*)&W[k * NOUT + c];
        acc.x = fmaf(a, w.x, acc.x);
        acc.y = fmaf(a, w.y, acc.y);
        acc.z = fmaf(a, w.z, acc.z);
        acc.w = fmaf(a, w.w, acc.w);
    }
    *(float4*)&part[kg][cl] = acc;
    __syncthreads();
    if (t < CPB) {
        float o = b[blockIdx.x * CPB + t];
#pragma unroll
        for (int gi = 0; gi < KG; ++gi) o += part[gi][t];
        out[row * NOUT + blockIdx.x * CPB + t] = o;
    }
}

extern "C" void kernel_launch(void* const* d_in, const int* in_sizes, int n_in,
                              void* d_out, int out_size, void* d_ws, size_t ws_size,
                              hipStream_t stream) {
    const int* x = (const int*)d_in[0];
    const float* W1 = (const float*)d_in[1];
    const float* b1 = (const float*)d_in[2];
    const float* g1 = (const float*)d_in[3];
    const float* be1 = (const float*)d_in[4];
    const float* W2 = (const float*)d_in[5];
    const float* b2 = (const float*)d_in[6];
    const float* g2 = (const float*)d_in[7];
    const float* be2 = (const float*)d_in[8];
    const float* W3 = (const float*)d_in[9];
    const float* b3 = (const float*)d_in[10];
    float* out = (float*)d_out;

    char* ws = (char*)d_ws;
    int* hist = (int*)ws;                    // 64*256*4 = 65536 B
    int* cnt = (int*)(ws + 65536);           // 64*64*4  = 16384 B
    float* feats = (float*)(ws + 81920);     // 64*321*4 = 82176 B -> ends 164096
    float* raw1 = (float*)(ws + 164096);     // 64*512*4 = 131072 B -> ends 295168
    float* raw2 = (float*)(ws + 295168);     // 64*512*4 = 131072 B -> ends 426240

    hipMemsetAsync(d_ws, 0, 81920, stream);  // zero hist + cnt (ws is poisoned)
    hist_kernel<<<dim3(8, 64), 256, 0, stream>>>(x, hist);
    went_kernel<<<dim3((NW + WPB - 1) / WPB, BATCH), 256, 0, stream>>>(x, cnt);
    feats_kernel<<<BATCH, 256, 0, stream>>>(hist, cnt, feats);
    gemm_first_kernel<<<dim3(8, BATCH), 256, 0, stream>>>(feats, W1, b1, raw1);
    gemm_ln_kernel<512, 64><<<dim3(8, BATCH), 256, 0, stream>>>(raw1, g1, be1, W2, b2, raw2);
    gemm_ln_kernel<256, 32><<<dim3(8, BATCH), 256, 0, stream>>>(raw2, g2, be2, W3, b3, out);
}

// Round 4
// 130.494 us; speedup vs baseline: 2.2356x; 1.0964x over previous
//
#include <hip/hip_runtime.h>

#define BATCH 64
#define LLEN 65536
#define NW 2047
#define STATS 321
#define NCHUNK 32   // chunks per row; each chunk = 2048 elements, 64 windows

__device__ __forceinline__ float waveReduceSum(float v) {
#pragma unroll
    for (int off = 32; off >= 1; off >>= 1) v += __shfl_xor(v, off, 64);
    return v;
}

// ---------------- fused front-end: per-chunk histogram + windowed entropy ----------------
// grid (NCHUNK, BATCH), 256 threads. Chunk c covers elements [2048c, 2048c+2048)
// and windows [64c, 64c+64). Writes per-block partials with plain stores
// (every slot written exactly once -> no zero-init of workspace needed).
__global__ __launch_bounds__(256) void front_kernel(const int* __restrict__ x,
                                                    int* __restrict__ hpart,
                                                    int* __restrict__ cpart) {
    __shared__ int lh[256];
    __shared__ int lcnt[64];
    const int row = blockIdx.y;
    const int c = blockIdx.x;
    const int t = threadIdx.x;
    lh[t] = 0;
    if (t < 64) lcnt[t] = 0;
    __syncthreads();

    // --- chunk histogram into LDS ---
    const int base = row * LLEN + c * 2048;
#pragma unroll
    for (int it = 0; it < 8; ++it) {
        int v = x[base + it * 256 + t];
        v = min(max(v, 0), 255);
        atomicAdd(&lh[v], 1);
    }

    // --- 16 windows per wave via ballot match-counting (reads are L1-hot) ---
    const int lane = t & 63;
    const int wave = t >> 6;
    const float lv = (lane == 63) ? 8.0f : (float)lane * (8.0f / 63.0f);
    const int wbase = c * 64 + wave * 16;
    const int rbase = row * LLEN;
#pragma unroll 2
    for (int i = 0; i < 16; ++i) {
        const int w = wbase + i;
        if (w < NW) {
            int v = x[rbase + (w << 5) + lane];
            v = min(max(v, 0), 255);
            unsigned long long m = ~0ull;
#pragma unroll
            for (int k = 0; k < 8; ++k) {
                unsigned long long b = __ballot((v >> k) & 1);
                m &= ((v >> k) & 1) ? b : ~b;
            }
            const float cc = (float)__popcll(m);
            // per-lane share: term(c)/c = -(1/64)*log2(c/64); butterfly broadcasts sum
            float e = waveReduceSum(-0.015625f * log2f(cc * 0.015625f));
            const unsigned long long mask = __ballot(e <= lv);
            if (lane == 0) atomicAdd(&lcnt[__ffsll((long long)mask) - 1], 1);
        }
    }
    __syncthreads();

    hpart[(row * NCHUNK + c) * 256 + t] = lh[t];
    if (t < 64) cpart[(row * NCHUNK + c) * 64 + t] = lcnt[t];
}

// ---------------- feats + MLP layer 1: [321] @ W1[321,512] + b1 -> raw1 ----------------
// grid (8, 64): 64-col tiles. Each block re-derives the 321-dim feature vector
// from the partials directly into LDS (cheap: 32KB L2 reads), then GEMMs.
__global__ __launch_bounds__(256) void gemm1_kernel(
    const int* __restrict__ hpart, const int* __restrict__ cpart,
    const float* __restrict__ W, const float* __restrict__ b,
    float* __restrict__ out) {
    __shared__ float sa[STATS];
    __shared__ float red[4];
    __shared__ float cb[64];
    __shared__ float part[16][64];
    const int row = blockIdx.y;
    const int t = threadIdx.x;

    // sum histogram partials over chunks
    int h = 0;
    const int* hp = hpart + row * (NCHUNK * 256) + t;
#pragma unroll
    for (int ch = 0; ch < NCHUNK; ++ch) h += hp[ch * 256];
    const float p = (float)h * (1.0f / 65536.0f);
    sa[t] = p;  // normalized hist (probs vs h/(L+1e-10) identical in f32)
    const float term = -p * log2f(p + 1e-10f);  // p==0 -> -0*log2(eps) = 0, matches ref
    const float s = waveReduceSum(term);
    if ((t & 63) == 0) red[t >> 6] = s;

    // sum CDF-bin partials over chunks
    if (t < 64) {
        int cc = 0;
        const int* cp = cpart + row * (NCHUNK * 64) + t;
#pragma unroll
        for (int ch = 0; ch < NCHUNK; ++ch) cc += cp[ch * 64];
        cb[t] = (float)cc;
    }
    __syncthreads();
    if (t == 0) sa[256] = red[0] + red[1] + red[2] + red[3];  // global entropy
    if (t < 64) {
        float cum = 0.0f;
        for (int k = 0; k <= t; ++k) cum += cb[k];  // LDS broadcasts, tiny
        sa[257 + t] = cum * (1.0f / 2047.0f);
    }
    __syncthreads();

    // GEMM: cols 64*blockIdx.x .. +63, K split 16 ways
    const int cl = (t & 15) * 4;
    const int col = blockIdx.x * 64 + cl;
    const int kg = t >> 4;
    const int klo = kg * 21;
    const int khi = min(klo + 21, STATS);
    float4 acc = {0.f, 0.f, 0.f, 0.f};
    for (int k = klo; k < khi; ++k) {
        const float a = sa[k];
        const float4 w = *(const float4*)&W[k * 512 + col];
        acc.x = fmaf(a, w.x, acc.x);
        acc.y = fmaf(a, w.y, acc.y);
        acc.z = fmaf(a, w.z, acc.z);
        acc.w = fmaf(a, w.w, acc.w);
    }
    *(float4*)&part[kg][cl] = acc;
    __syncthreads();
    if (t < 64) {
        float o = b[blockIdx.x * 64 + t];
#pragma unroll
        for (int g = 0; g < 16; ++g) o += part[g][t];
        out[row * 512 + blockIdx.x * 64 + t] = o;
    }
}

// ---------------- MLP layers 2/3: LN(raw)+ReLU then @ W + b ----------------
// grid (NOUT/CPB, 64). 256 threads. Input is 512-dim raw pre-LN activations.
template <int NOUT, int CPB>
__global__ __launch_bounds__(256) void gemm_ln_kernel(
    const float* __restrict__ raw, const float* __restrict__ g,
    const float* __restrict__ be, const float* __restrict__ W,
    const float* __restrict__ b, float* __restrict__ out) {
    constexpr int TC = CPB / 4;    // threads in col dim
    constexpr int KG = 256 / TC;   // k groups
    constexpr int KI = 512 / KG;   // k iters per thread
    __shared__ float sa[512];
    __shared__ float red[4];
    __shared__ float part[KG][CPB];
    const int row = blockIdx.y;
    const int t = threadIdx.x;

    const float v1 = raw[row * 512 + t];
    const float v2 = raw[row * 512 + 256 + t];
    float s = waveReduceSum(v1 + v2);
    if ((t & 63) == 0) red[t >> 6] = s;
    __syncthreads();
    const float mu = (red[0] + red[1] + red[2] + red[3]) * (1.0f / 512.0f);
    __syncthreads();
    float q = waveReduceSum(v1 * v1 + v2 * v2);
    if ((t & 63) == 0) red[t >> 6] = q;
    __syncthreads();
    const float var = (red[0] + red[1] + red[2] + red[3]) * (1.0f / 512.0f) - mu * mu;
    const float rs = rsqrtf(var + 1e-5f);
    sa[t] = fmaxf((v1 - mu) * rs * g[t] + be[t], 0.0f);
    sa[t + 256] = fmaxf((v2 - mu) * rs * g[t + 256] + be[t + 256], 0.0f);
    __syncthreads();

    const int cl = (t % TC) * 4;
    const int col = blockIdx.x * CPB + cl;
    const int kg = t / TC;
    float4 acc = {0.f, 0.f, 0.f, 0.f};
#pragma unroll
    for (int i = 0; i < KI; ++i) {
        const int k = kg * KI + i;
        const float a = sa[k];
        const float4 w = *(const float4*)&W[k * NOUT + col];
        acc.x = fmaf(a, w.x, acc.x);
        acc.y = fmaf(a, w.y, acc.y);
        acc.z = fmaf(a, w.z, acc.z);
        acc.w = fmaf(a, w.w, acc.w);
    }
    *(float4*)&part[kg][cl] = acc;
    __syncthreads();
    if (t < CPB) {
        float o = b[blockIdx.x * CPB + t];
#pragma unroll
        for (int gi = 0; gi < KG; ++gi) o += part[gi][t];
        out[row * NOUT + blockIdx.x * CPB + t] = o;
    }
}

extern "C" void kernel_launch(void* const* d_in, const int* in_sizes, int n_in,
                              void* d_out, int out_size, void* d_ws, size_t ws_size,
                              hipStream_t stream) {
    const int* x = (const int*)d_in[0];
    const float* W1 = (const float*)d_in[1];
    const float* b1 = (const float*)d_in[2];
    const float* g1 = (const float*)d_in[3];
    const float* be1 = (const float*)d_in[4];
    const float* W2 = (const float*)d_in[5];
    const float* b2 = (const float*)d_in[6];
    const float* g2 = (const float*)d_in[7];
    const float* be2 = (const float*)d_in[8];
    const float* W3 = (const float*)d_in[9];
    const float* b3 = (const float*)d_in[10];
    float* out = (float*)d_out;

    char* ws = (char*)d_ws;
    int* hpart = (int*)ws;                     // 64*32*256*4 = 2 MiB
    int* cpart = (int*)(ws + 2097152);         // 64*32*64*4  = 512 KiB
    float* raw1 = (float*)(ws + 2621440);      // 64*512*4 = 128 KiB
    float* raw2 = (float*)(ws + 2752512);      // 64*512*4 = 128 KiB

    // 4 dispatches, no memset: all workspace slots are written before read.
    front_kernel<<<dim3(NCHUNK, BATCH), 256, 0, stream>>>(x, hpart, cpart);
    gemm1_kernel<<<dim3(8, BATCH), 256, 0, stream>>>(hpart, cpart, W1, b1, raw1);
    gemm_ln_kernel<512, 64><<<dim3(8, BATCH), 256, 0, stream>>>(raw1, g1, be1, W2, b2, raw2);
    gemm_ln_kernel<256, 32><<<dim3(8, BATCH), 256, 0, stream>>>(raw2, g2, be2, W3, b3, out);
}

// Round 5
// 125.437 us; speedup vs baseline: 2.3258x; 1.0403x over previous
//
#include <hip/hip_runtime.h>

#define BATCH 64
#define LLEN 65536
#define NW 2047
#define STATS 321
#define NCHUNK 32   // chunks per row; each chunk = 2048 elements, 64 windows

// ---- wave64 sum via DPP (6 VALU adds), result broadcast via readlane ----
__device__ __forceinline__ float dppWaveSumBcast(float x) {
    float t;
    t = __int_as_float(__builtin_amdgcn_update_dpp(0, __float_as_int(x), 0x111, 0xf, 0xf, true));  x += t; // row_shr:1
    t = __int_as_float(__builtin_amdgcn_update_dpp(0, __float_as_int(x), 0x112, 0xf, 0xf, true));  x += t; // row_shr:2
    t = __int_as_float(__builtin_amdgcn_update_dpp(0, __float_as_int(x), 0x114, 0xf, 0xf, true));  x += t; // row_shr:4
    t = __int_as_float(__builtin_amdgcn_update_dpp(0, __float_as_int(x), 0x118, 0xf, 0xf, true));  x += t; // row_shr:8
    t = __int_as_float(__builtin_amdgcn_update_dpp(0, __float_as_int(x), 0x142, 0xa, 0xf, false)); x += t; // row_bcast:15 -> rows 1,3
    t = __int_as_float(__builtin_amdgcn_update_dpp(0, __float_as_int(x), 0x143, 0xc, 0xf, false)); x += t; // row_bcast:31 -> rows 2,3
    return __int_as_float(__builtin_amdgcn_readlane(__float_as_int(x), 63)); // uniform
}

// ---------------- fused front-end: per-chunk histogram + windowed entropy ----------------
// grid (NCHUNK, BATCH), 256 threads. Chunk c covers elements [2048c, 2048c+2048)
// and windows [64c, 64c+64). Plain-store partials (no zero-init needed).
__global__ __launch_bounds__(256) void front_kernel(const int* __restrict__ x,
                                                    int* __restrict__ hpart,
                                                    int* __restrict__ cpart) {
    __shared__ int lh[256];
    __shared__ int lcnt[64];
    const int row = blockIdx.y;
    const int c = blockIdx.x;
    const int t = threadIdx.x;
    lh[t] = 0;
    if (t < 64) lcnt[t] = 0;
    __syncthreads();

    // --- chunk histogram into LDS ---
    const int base = row * LLEN + c * 2048;
#pragma unroll
    for (int it = 0; it < 8; ++it) {
        int v = x[base + it * 256 + t];
        v = min(max(v, 0), 255);
        atomicAdd(&lh[v], 1);
    }

    // --- 16 windows per wave via ballot match-counting ---
    const int lane = t & 63;
    const int wave = t >> 6;
    const float lv = (lane == 63) ? 8.0f : (float)lane * (8.0f / 63.0f);
    const int wbase = c * 64 + wave * 16;
    const int rbase = row * LLEN;

    int vv[16];
#pragma unroll
    for (int i = 0; i < 16; ++i) {
        const int w = wbase + i;
        vv[i] = (w < NW) ? x[rbase + (w << 5) + lane] : 0;  // L1-hot (chunk just read)
    }
#pragma unroll
    for (int i = 0; i < 16; ++i) {
        const int w = wbase + i;  // uniform per wave
        if (w < NW) {
            const int v = min(max(vv[i], 0), 255);
            unsigned long long m = ~0ull;
#pragma unroll
            for (int k = 0; k < 8; ++k) {
                const int bit = (v >> k) & 1;
                const unsigned long long b = __ballot(bit);
                m &= bit ? b : ~b;
            }
            const int cc = __popcll(m);  // multiplicity of this lane's byte
            // entropy = sum over lanes of -(1/64)*log2(c/64)/c-grouped -> per-lane share
            const float e = dppWaveSumBcast(-0.015625f * __log2f((float)cc * 0.015625f));
            const unsigned long long mask = __ballot(e <= lv);
            if (lane == 0) atomicAdd(&lcnt[__ffsll((long long)mask) - 1], 1);
        }
    }
    __syncthreads();

    hpart[(row * NCHUNK + c) * 256 + t] = lh[t];
    if (t < 64) cpart[(row * NCHUNK + c) * 64 + t] = lcnt[t];
}

// ---------------- feats + MLP layer 1: [321] @ W1[321,512] + b1 -> raw1 ----------------
__global__ __launch_bounds__(256) void gemm1_kernel(
    const int* __restrict__ hpart, const int* __restrict__ cpart,
    const float* __restrict__ W, const float* __restrict__ b,
    float* __restrict__ out) {
    __shared__ float sa[STATS];
    __shared__ float red[4];
    __shared__ float cb[64];
    __shared__ float part[16][64];
    const int row = blockIdx.y;
    const int t = threadIdx.x;

    // sum histogram partials over chunks
    int h = 0;
    const int* hp = hpart + row * (NCHUNK * 256) + t;
#pragma unroll
    for (int ch = 0; ch < NCHUNK; ++ch) h += hp[ch * 256];
    const float p = (float)h * (1.0f / 65536.0f);
    sa[t] = p;
    const float term = -p * log2f(p + 1e-10f);  // p==0 -> 0, matches ref
    const float s = dppWaveSumBcast(term);
    if ((t & 63) == 0) red[t >> 6] = s;

    if (t < 64) {
        int cc = 0;
        const int* cp = cpart + row * (NCHUNK * 64) + t;
#pragma unroll
        for (int ch = 0; ch < NCHUNK; ++ch) cc += cp[ch * 64];
        cb[t] = (float)cc;
    }
    __syncthreads();
    if (t == 0) sa[256] = red[0] + red[1] + red[2] + red[3];  // global entropy
    if (t < 64) {
        float cum = 0.0f;
        for (int k = 0; k <= t; ++k) cum += cb[k];
        sa[257 + t] = cum * (1.0f / 2047.0f);
    }
    __syncthreads();

    const int cl = (t & 15) * 4;
    const int col = blockIdx.x * 64 + cl;
    const int kg = t >> 4;
    const int klo = kg * 21;
    const int khi = min(klo + 21, STATS);
    float4 acc = {0.f, 0.f, 0.f, 0.f};
    for (int k = klo; k < khi; ++k) {
        const float a = sa[k];
        const float4 w = *(const float4*)&W[k * 512 + col];
        acc.x = fmaf(a, w.x, acc.x);
        acc.y = fmaf(a, w.y, acc.y);
        acc.z = fmaf(a, w.z, acc.z);
        acc.w = fmaf(a, w.w, acc.w);
    }
    *(float4*)&part[kg][cl] = acc;
    __syncthreads();
    if (t < 64) {
        float o = b[blockIdx.x * 64 + t];
#pragma unroll
        for (int g = 0; g < 16; ++g) o += part[g][t];
        out[row * 512 + blockIdx.x * 64 + t] = o;
    }
}

// ---------------- MLP layers 2/3: LN(raw)+ReLU then @ W + b ----------------
template <int NOUT, int CPB>
__global__ __launch_bounds__(256) void gemm_ln_kernel(
    const float* __restrict__ raw, const float* __restrict__ g,
    const float* __restrict__ be, const float* __restrict__ W,
    const float* __restrict__ b, float* __restrict__ out) {
    constexpr int TC = CPB / 4;
    constexpr int KG = 256 / TC;
    constexpr int KI = 512 / KG;
    __shared__ float sa[512];
    __shared__ float red[8];
    __shared__ float part[KG][CPB];
    const int row = blockIdx.y;
    const int t = threadIdx.x;

    const float v1 = raw[row * 512 + t];
    const float v2 = raw[row * 512 + 256 + t];
    const float s = dppWaveSumBcast(v1 + v2);
    const float q = dppWaveSumBcast(v1 * v1 + v2 * v2);
    if ((t & 63) == 0) { red[t >> 6] = s; red[4 + (t >> 6)] = q; }
    __syncthreads();
    const float mu = (red[0] + red[1] + red[2] + red[3]) * (1.0f / 512.0f);
    const float var = (red[4] + red[5] + red[6] + red[7]) * (1.0f / 512.0f) - mu * mu;
    const float rs = rsqrtf(var + 1e-5f);
    sa[t] = fmaxf((v1 - mu) * rs * g[t] + be[t], 0.0f);
    sa[t + 256] = fmaxf((v2 - mu) * rs * g[t + 256] + be[t + 256], 0.0f);
    __syncthreads();

    const int cl = (t % TC) * 4;
    const int col = blockIdx.x * CPB + cl;
    const int kg = t / TC;
    float4 acc = {0.f, 0.f, 0.f, 0.f};
#pragma unroll
    for (int i = 0; i < KI; ++i) {
        const int k = kg * KI + i;
        const float a = sa[k];
        const float4 w = *(const float4*)&W[k * NOUT + col];
        acc.x = fmaf(a, w.x, acc.x);
        acc.y = fmaf(a, w.y, acc.y);
        acc.z = fmaf(a, w.z, acc.z);
        acc.w = fmaf(a, w.w, acc.w);
    }
    *(float4*)&part[kg][cl] = acc;
    __syncthreads();
    if (t < CPB) {
        float o = b[blockIdx.x * CPB + t];
#pragma unroll
        for (int gi = 0; gi < KG; ++gi) o += part[gi][t];
        out[row * NOUT + blockIdx.x * CPB + t] = o;
    }
}

extern "C" void kernel_launch(void* const* d_in, const int* in_sizes, int n_in,
                              void* d_out, int out_size, void* d_ws, size_t ws_size,
                              hipStream_t stream) {
    const int* x = (const int*)d_in[0];
    const float* W1 = (const float*)d_in[1];
    const float* b1 = (const float*)d_in[2];
    const float* g1 = (const float*)d_in[3];
    const float* be1 = (const float*)d_in[4];
    const float* W2 = (const float*)d_in[5];
    const float* b2 = (const float*)d_in[6];
    const float* g2 = (const float*)d_in[7];
    const float* be2 = (const float*)d_in[8];
    const float* W3 = (const float*)d_in[9];
    const float* b3 = (const float*)d_in[10];
    float* out = (float*)d_out;

    char* ws = (char*)d_ws;
    int* hpart = (int*)ws;                     // 64*32*256*4 = 2 MiB
    int* cpart = (int*)(ws + 2097152);         // 64*32*64*4  = 512 KiB
    float* raw1 = (float*)(ws + 2621440);      // 64*512*4 = 128 KiB
    float* raw2 = (float*)(ws + 2752512);      // 64*512*4 = 128 KiB

    front_kernel<<<dim3(NCHUNK, BATCH), 256, 0, stream>>>(x, hpart, cpart);
    gemm1_kernel<<<dim3(8, BATCH), 256, 0, stream>>>(hpart, cpart, W1, b1, raw1);
    gemm_ln_kernel<512, 64><<<dim3(8, BATCH), 256, 0, stream>>>(raw1, g1, be1, W2, b2, raw2);
    gemm_ln_kernel<256, 32><<<dim3(8, BATCH), 256, 0, stream>>>(raw2, g2, be2, W3, b3, out);
}

// Round 6
// 119.588 us; speedup vs baseline: 2.4395x; 1.0489x over previous
//
#include <hip/hip_runtime.h>

#define BATCH 64
#define LLEN 65536
#define NW 2047
#define STATS 321
#define NCHUNK 32   // chunks per row; each chunk = 2048 elements, 64 windows

// ---- wave64 sum via DPP (6 VALU adds); returns total (lane-63 value) uniform ----
__device__ __forceinline__ float dppWaveSumBcast(float x) {
    float t;
    t = __int_as_float(__builtin_amdgcn_update_dpp(0, __float_as_int(x), 0x111, 0xf, 0xf, true));  x += t; // row_shr:1
    t = __int_as_float(__builtin_amdgcn_update_dpp(0, __float_as_int(x), 0x112, 0xf, 0xf, true));  x += t; // row_shr:2
    t = __int_as_float(__builtin_amdgcn_update_dpp(0, __float_as_int(x), 0x114, 0xf, 0xf, true));  x += t; // row_shr:4
    t = __int_as_float(__builtin_amdgcn_update_dpp(0, __float_as_int(x), 0x118, 0xf, 0xf, true));  x += t; // row_shr:8
    t = __int_as_float(__builtin_amdgcn_update_dpp(0, __float_as_int(x), 0x142, 0xa, 0xf, false)); x += t; // row_bcast:15
    t = __int_as_float(__builtin_amdgcn_update_dpp(0, __float_as_int(x), 0x143, 0xc, 0xf, false)); x += t; // row_bcast:31
    return __int_as_float(__builtin_amdgcn_readlane(__float_as_int(x), 63));
}

// ---------------- fused front-end: per-chunk histogram + windowed entropy ----------------
// grid (NCHUNK, BATCH), 256 threads. Chunk c: elements [2048c,2048c+2048),
// windows [64c,64c+64). Lane k of each wave owns CDF level k: counts windows
// with entropy <= level_k directly (no binning, no atomics, no prefix sum).
__global__ __launch_bounds__(256) void front_kernel(const int* __restrict__ x,
                                                    int* __restrict__ hpart,
                                                    int* __restrict__ cpart) {
    __shared__ int lh[256];
    __shared__ int lc[256];
    const int row = blockIdx.y;
    const int c = blockIdx.x;
    const int t = threadIdx.x;
    lh[t] = 0;
    __syncthreads();

    // --- chunk histogram into LDS ---
    const int base = row * LLEN + c * 2048;
#pragma unroll
    for (int it = 0; it < 8; ++it) {
        int v = x[base + it * 256 + t];
        atomicAdd(&lh[min(max(v, 0), 255)], 1);
    }

    // --- 16 windows per wave via ballot match-counting ---
    const int lane = t & 63;
    const int wave = t >> 6;
    // e <= lv  <=>  S >= (6 - lv)*64, where S = sum_lanes log2(c_lane)
    const float lv = (lane == 63) ? 8.0f : (float)lane * (8.0f / 63.0f);
    const float T = (6.0f - lv) * 64.0f;
    const int wbase = c * 64 + wave * 16;

    int vv[16];
#pragma unroll
    for (int i = 0; i < 16; ++i) {
        const int w = min(wbase + i, NW - 1);  // clamp lone OOB window (masked below)
        vv[i] = x[row * LLEN + (w << 5) + lane];
    }
    int cnt = 0;
#pragma unroll
    for (int i = 0; i < 16; ++i) {
        const int v = vv[i];
        unsigned long long m = ~0ull;
#pragma unroll
        for (int k = 0; k < 8; ++k) {
            const unsigned long long b = __ballot(v & (1 << k));
            m &= ((v >> k) & 1) ? b : ~b;
        }
        const float S = dppWaveSumBcast(__log2f((float)__popcll(m)));
        cnt += (int)((S >= T) && (wbase + i < NW));
    }
    lc[t] = cnt;
    __syncthreads();

    hpart[(row * NCHUNK + c) * 256 + t] = lh[t];
    if (t < 64)
        cpart[(row * NCHUNK + c) * 64 + t] = lc[t] + lc[64 + t] + lc[128 + t] + lc[192 + t];
}

// ---------------- feats + MLP layer 1: [321] @ W1[321,512] + b1 -> raw1 ----------------
__global__ __launch_bounds__(256) void gemm1_kernel(
    const int* __restrict__ hpart, const int* __restrict__ cpart,
    const float* __restrict__ W, const float* __restrict__ b,
    float* __restrict__ out) {
    __shared__ float sa[STATS];
    __shared__ float red[4];
    __shared__ float part[16][64];
    const int row = blockIdx.y;
    const int t = threadIdx.x;

    // sum histogram partials over chunks
    int h = 0;
    const int* hp = hpart + row * (NCHUNK * 256) + t;
#pragma unroll
    for (int ch = 0; ch < NCHUNK; ++ch) h += hp[ch * 256];
    const float p = (float)h * (1.0f / 65536.0f);
    sa[t] = p;
    const float term = -p * log2f(p + 1e-10f);  // p==0 -> 0, matches ref
    const float s = dppWaveSumBcast(term);
    if ((t & 63) == 0) red[t >> 6] = s;

    // per-level CDF counts are already cumulative in meaning
    if (t < 64) {
        int cc = 0;
        const int* cp = cpart + row * (NCHUNK * 64) + t;
#pragma unroll
        for (int ch = 0; ch < NCHUNK; ++ch) cc += cp[ch * 64];
        sa[257 + t] = (float)cc * (1.0f / 2047.0f);
    }
    __syncthreads();
    if (t == 0) sa[256] = red[0] + red[1] + red[2] + red[3];  // global entropy
    __syncthreads();

    const int cl = (t & 15) * 4;
    const int col = blockIdx.x * 64 + cl;
    const int kg = t >> 4;
    const int klo = kg * 21;
    const int khi = min(klo + 21, STATS);
    float4 acc = {0.f, 0.f, 0.f, 0.f};
    for (int k = klo; k < khi; ++k) {
        const float a = sa[k];
        const float4 w = *(const float4*)&W[k * 512 + col];
        acc.x = fmaf(a, w.x, acc.x);
        acc.y = fmaf(a, w.y, acc.y);
        acc.z = fmaf(a, w.z, acc.z);
        acc.w = fmaf(a, w.w, acc.w);
    }
    *(float4*)&part[kg][cl] = acc;
    __syncthreads();
    if (t < 64) {
        float o = b[blockIdx.x * 64 + t];
#pragma unroll
        for (int g = 0; g < 16; ++g) o += part[g][t];
        out[row * 512 + blockIdx.x * 64 + t] = o;
    }
}

// ---------------- MLP layers 2/3: LN(raw)+ReLU then @ W + b ----------------
template <int NOUT, int CPB>
__global__ __launch_bounds__(256) void gemm_ln_kernel(
    const float* __restrict__ raw, const float* __restrict__ g,
    const float* __restrict__ be, const float* __restrict__ W,
    const float* __restrict__ b, float* __restrict__ out) {
    constexpr int TC = CPB / 4;
    constexpr int KG = 256 / TC;
    constexpr int KI = 512 / KG;
    __shared__ float sa[512];
    __shared__ float red[8];
    __shared__ float part[KG][CPB];
    const int row = blockIdx.y;
    const int t = threadIdx.x;

    const float v1 = raw[row * 512 + t];
    const float v2 = raw[row * 512 + 256 + t];
    const float s = dppWaveSumBcast(v1 + v2);
    const float q = dppWaveSumBcast(v1 * v1 + v2 * v2);
    if ((t & 63) == 0) { red[t >> 6] = s; red[4 + (t >> 6)] = q; }
    __syncthreads();
    const float mu = (red[0] + red[1] + red[2] + red[3]) * (1.0f / 512.0f);
    const float var = (red[4] + red[5] + red[6] + red[7]) * (1.0f / 512.0f) - mu * mu;
    const float rs = rsqrtf(var + 1e-5f);
    sa[t] = fmaxf((v1 - mu) * rs * g[t] + be[t], 0.0f);
    sa[t + 256] = fmaxf((v2 - mu) * rs * g[t + 256] + be[t + 256], 0.0f);
    __syncthreads();

    const int cl = (t % TC) * 4;
    const int col = blockIdx.x * CPB + cl;
    const int kg = t / TC;
    float4 acc = {0.f, 0.f, 0.f, 0.f};
#pragma unroll
    for (int i = 0; i < KI; ++i) {
        const int k = kg * KI + i;
        const float a = sa[k];
        const float4 w = *(const float4*)&W[k * NOUT + col];
        acc.x = fmaf(a, w.x, acc.x);
        acc.y = fmaf(a, w.y, acc.y);
        acc.z = fmaf(a, w.z, acc.z);
        acc.w = fmaf(a, w.w, acc.w);
    }
    *(float4*)&part[kg][cl] = acc;
    __syncthreads();
    if (t < CPB) {
        float o = b[blockIdx.x * CPB + t];
#pragma unroll
        for (int gi = 0; gi < KG; ++gi) o += part[gi][t];
        out[row * NOUT + blockIdx.x * CPB + t] = o;
    }
}

extern "C" void kernel_launch(void* const* d_in, const int* in_sizes, int n_in,
                              void* d_out, int out_size, void* d_ws, size_t ws_size,
                              hipStream_t stream) {
    const int* x = (const int*)d_in[0];
    const float* W1 = (const float*)d_in[1];
    const float* b1 = (const float*)d_in[2];
    const float* g1 = (const float*)d_in[3];
    const float* be1 = (const float*)d_in[4];
    const float* W2 = (const float*)d_in[5];
    const float* b2 = (const float*)d_in[6];
    const float* g2 = (const float*)d_in[7];
    const float* be2 = (const float*)d_in[8];
    const float* W3 = (const float*)d_in[9];
    const float* b3 = (const float*)d_in[10];
    float* out = (float*)d_out;

    char* ws = (char*)d_ws;
    int* hpart = (int*)ws;                     // 64*32*256*4 = 2 MiB
    int* cpart = (int*)(ws + 2097152);         // 64*32*64*4  = 512 KiB
    float* raw1 = (float*)(ws + 2621440);      // 64*512*4 = 128 KiB
    float* raw2 = (float*)(ws + 2752512);      // 64*512*4 = 128 KiB

    front_kernel<<<dim3(NCHUNK, BATCH), 256, 0, stream>>>(x, hpart, cpart);
    gemm1_kernel<<<dim3(8, BATCH), 256, 0, stream>>>(hpart, cpart, W1, b1, raw1);
    gemm_ln_kernel<512, 64><<<dim3(8, BATCH), 256, 0, stream>>>(raw1, g1, be1, W2, b2, raw2);
    gemm_ln_kernel<256, 32><<<dim3(8, BATCH), 256, 0, stream>>>(raw2, g2, be2, W3, b3, out);
}